// Round 4
// baseline (295.738 us; speedup 1.0000x reference)
//
#include <hip/hip_runtime.h>
#include <hip/hip_bf16.h>
#include <math.h>

// GCN forward, bf16 compute / fp32 accumulate:
//   prep: W1T=bf16(W1^T), W2T=bf16(W2^T), row_ptr from sorted COO rows
//   h1  = bf16( x @ W1 )             [50000,128]  MFMA 16x16x32 bf16
//   h2  = bf16( relu(A @ h1 + b1) )  [50000,128]  wave-per-row gather SpMM
//   t   = bf16( h2 @ W2 )            [50000,64]   MFMA, W2 frags in registers
//   out = log_softmax(A @ t + b2)    [50000,64]   fp32, wave-per-row
//
// Grid sizes capped (~1-2k blocks) + grid-stride: avoids 50k-workgroup
// dispatch overhead and gives full wave occupancy (G11).

#define N_NODES 50000
#define N_EDGES 800000
#define NFEAT   512
#define NHID    128
#define NCLASS  64

typedef short  short8  __attribute__((ext_vector_type(8)));
typedef unsigned short ushort8 __attribute__((ext_vector_type(8)));
typedef float  f32x4   __attribute__((ext_vector_type(4)));

static __device__ __forceinline__ float bflo(unsigned int p) {
    return __builtin_bit_cast(float, p << 16);
}
static __device__ __forceinline__ float bfhi(unsigned int p) {
    return __builtin_bit_cast(float, p & 0xFFFF0000u);
}
static __device__ __forceinline__ unsigned short f2bf(float f) {
    unsigned int b = __builtin_bit_cast(unsigned int, f);
    return (unsigned short)((b + 0x7FFFu + ((b >> 16) & 1u)) >> 16);  // RNE
}

// ---------------------------------------------------------------------------
// prep: row_ptr build + W1T[n][k]=bf16(W1[k][n]) + W2T[n][k]=bf16(W2[k][n])
// ---------------------------------------------------------------------------
__global__ __launch_bounds__(256) void prep_kernel(
        const float* __restrict__ W1, const float* __restrict__ W2,
        const int* __restrict__ rows,
        unsigned short* __restrict__ W1T, unsigned short* __restrict__ W2T,
        int* __restrict__ row_ptr) {
    const int tid = blockIdx.x * 256 + threadIdx.x;
    const int T   = gridDim.x * 256;
    for (int e = tid; e < N_EDGES; e += T) {
        const int re = rows[e];
        if (e == 0) {
            for (int r = 0; r <= re; ++r) row_ptr[r] = 0;
        } else {
            const int rp = rows[e - 1];
            for (int r = rp + 1; r <= re; ++r) row_ptr[r] = e;
        }
        if (e == N_EDGES - 1) {
            for (int r = re + 1; r <= N_NODES; ++r) row_ptr[r] = N_EDGES;
        }
    }
    for (int i = tid; i < NHID * NFEAT; i += T) {
        const int n = i >> 9, k = i & 511;
        W1T[i] = f2bf(W1[(size_t)k * NHID + n]);
    }
    for (int i = tid; i < NCLASS * NHID; i += T) {
        const int n = i >> 7, k = i & 127;
        W2T[i] = f2bf(W2[(size_t)k * NCLASS + n]);
    }
}

// ---------------------------------------------------------------------------
// GEMM1 (MFMA): h1b[M,128] = bf16( x[M,512] @ W1[512,128] )
// BM=64 (782 blocks -> ~3 blocks/CU), BN=128, BK=64; 4 waves (2 row x 2 col),
// per wave 32x64 out = 2x4 fragments, two K=32 MFMA steps per K-tile.
// LDS elem (row,k) at byte row*128 + (((k>>3) ^ (row&7))<<4) + (k&7)*2 —
// XOR-swizzled 16B granules, conflict-free staging writes and frag reads.
// k-slot consistency: lane's A slot j and B slot j carry the SAME k, so
// D = A.B independent of HW internal k order (validated R3 on hardware).
// ---------------------------------------------------------------------------
__global__ __launch_bounds__(256) void gemm1_kernel(
        const float* __restrict__ x, const unsigned short* __restrict__ W1T,
        unsigned short* __restrict__ h1b, int M) {
    __shared__ unsigned short sA[64 * 64];    // 8 KB
    __shared__ unsigned short sB[128 * 64];   // 16 KB

    const int tid  = threadIdx.x;
    const int lane = tid & 63;
    const int wid  = tid >> 6;
    const int wr   = wid >> 1, wc = wid & 1;
    const int row0 = blockIdx.x * 64;

    f32x4 acc[2][4];
    #pragma unroll
    for (int i = 0; i < 2; ++i)
        #pragma unroll
        for (int j = 0; j < 4; ++j)
            acc[i][j] = (f32x4){0.f, 0.f, 0.f, 0.f};

    const int arow = tid >> 2;           // 0..63
    const int akc  = (tid & 3) * 16;     // 16-float k-chunk
    const int bcol = tid >> 1;           // 0..127
    const int bkh  = (tid & 1) * 32;     // 32-ushort k-half

    for (int kt = 0; kt < NFEAT; kt += 64) {
        // stage A: x fp32 -> bf16, swizzled
        {
            float v[16];
            const float* src = x + (size_t)(row0 + arow) * NFEAT + kt + akc;
            if (row0 + arow < M) {
                #pragma unroll
                for (int i = 0; i < 4; ++i)
                    *(float4*)&v[i * 4] = *(const float4*)(src + i * 4);
            } else {
                #pragma unroll
                for (int i = 0; i < 16; ++i) v[i] = 0.f;
            }
            #pragma unroll
            for (int i2 = 0; i2 < 2; ++i2) {
                ushort8 w;
                #pragma unroll
                for (int q = 0; q < 8; ++q) w[q] = f2bf(v[i2 * 8 + q]);
                const int gran = ((akc >> 3) + i2) ^ (arow & 7);
                *(ushort8*)((char*)sA + arow * 128 + gran * 16) = w;
            }
        }
        // stage B: W1T bf16, swizzled
        {
            const unsigned short* srcb = W1T + (size_t)bcol * NFEAT + kt + bkh;
            #pragma unroll
            for (int i = 0; i < 4; ++i) {
                ushort8 w = *(const ushort8*)(srcb + i * 8);
                const int gran = ((bkh >> 3) + i) ^ (bcol & 7);
                *(ushort8*)((char*)sB + bcol * 128 + gran * 16) = w;
            }
        }
        __syncthreads();

        #pragma unroll
        for (int ks = 0; ks < 2; ++ks) {
            short8 af[2], bfr[4];
            #pragma unroll
            for (int i = 0; i < 2; ++i) {
                const int ar = wr * 32 + i * 16 + (lane & 15);
                const int gran = (ks * 4 + (lane >> 4)) ^ (ar & 7);
                af[i] = *(const short8*)((const char*)sA + ar * 128 + gran * 16);
            }
            #pragma unroll
            for (int j = 0; j < 4; ++j) {
                const int br = wc * 64 + j * 16 + (lane & 15);
                const int gran = (ks * 4 + (lane >> 4)) ^ (br & 7);
                bfr[j] = *(const short8*)((const char*)sB + br * 128 + gran * 16);
            }
            #pragma unroll
            for (int i = 0; i < 2; ++i)
                #pragma unroll
                for (int j = 0; j < 4; ++j)
                    acc[i][j] = __builtin_amdgcn_mfma_f32_16x16x32_bf16(
                        af[i], bfr[j], acc[i][j], 0, 0, 0);
        }
        __syncthreads();
    }

    const int cr = (lane >> 4) * 4;
    const int cc = lane & 15;
    #pragma unroll
    for (int i = 0; i < 2; ++i)
        #pragma unroll
        for (int j = 0; j < 4; ++j)
            #pragma unroll
            for (int reg = 0; reg < 4; ++reg) {
                const int row = row0 + wr * 32 + i * 16 + cr + reg;
                const int col = wc * 64 + j * 16 + cc;
                if (row < M)
                    h1b[(size_t)row * NHID + col] = f2bf(acc[i][j][reg]);
            }
}

// ---------------------------------------------------------------------------
// SpMM1: h2b[r,:] = bf16(relu( sum_e vals[e]*h1b[cols[e],:] + b1 )).
// 256-thr blocks, wave per row, grid-stride; 8-edge unroll (8 gathers in
// flight). Lane j holds feats {2j,2j+1} via uint gather (256B/edge/wave).
// ---------------------------------------------------------------------------
__global__ __launch_bounds__(256) void spmm1_kernel(
        const int* __restrict__ row_ptr, const int* __restrict__ cols,
        const float* __restrict__ vals, const unsigned short* __restrict__ h1b,
        const float* __restrict__ b1, unsigned short* __restrict__ h2b,
        int nwaves) {
    const int j    = threadIdx.x & 63;
    const int wave = (blockIdx.x * 256 + threadIdx.x) >> 6;
    const float bb0 = b1[2 * j], bb1 = b1[2 * j + 1];

    for (int r = wave; r < N_NODES; r += nwaves) {
        const int lo = row_ptr[r], hi = row_ptr[r + 1];
        float a0 = 0.f, a1 = 0.f;
        int e = lo;
        for (; e + 8 <= hi; e += 8) {
            unsigned int p[8];
            float v[8];
            #pragma unroll
            for (int q = 0; q < 8; ++q) {
                const int c = cols[e + q];
                v[q] = vals[e + q];
                p[q] = *(const unsigned int*)(h1b + (size_t)c * NHID + 2 * j);
            }
            #pragma unroll
            for (int q = 0; q < 8; ++q) {
                a0 = fmaf(v[q], bflo(p[q]), a0);
                a1 = fmaf(v[q], bfhi(p[q]), a1);
            }
        }
        for (; e < hi; ++e) {
            const float vv = vals[e];
            unsigned int p = *(const unsigned int*)(h1b + (size_t)cols[e] * NHID + 2 * j);
            a0 = fmaf(vv, bflo(p), a0);
            a1 = fmaf(vv, bfhi(p), a1);
        }
        a0 += bb0; a1 += bb1;
        a0 = a0 > 0.f ? a0 : 0.f;
        a1 = a1 > 0.f ? a1 : 0.f;
        *(unsigned int*)(h2b + (size_t)r * NHID + 2 * j) =
            (unsigned int)f2bf(a0) | ((unsigned int)f2bf(a1) << 16);
    }
}

// ---------------------------------------------------------------------------
// GEMM2 (MFMA): tb[50000,64] = bf16( h2b @ W2 ).  W2T fragments live in
// registers (16 x ushort8); wave per 16-row tile (50000 = 3125*16, no tail).
// ---------------------------------------------------------------------------
__global__ __launch_bounds__(256) void gemm2_kernel(
        const unsigned short* __restrict__ h2b,
        const unsigned short* __restrict__ W2T,
        unsigned short* __restrict__ tb, int nwaves) {
    const int lane = threadIdx.x & 63;
    const int wave = (blockIdx.x * 256 + threadIdx.x) >> 6;
    const int l15 = lane & 15, lg = lane >> 4;

    short8 Bf[4][4];
    #pragma unroll
    for (int ks = 0; ks < 4; ++ks)
        #pragma unroll
        for (int ct = 0; ct < 4; ++ct)
            Bf[ks][ct] = *(const short8*)(W2T + (size_t)(ct * 16 + l15) * NHID + ks * 32 + lg * 8);

    const int ntiles = N_NODES / 16;    // 3125
    for (int t = wave; t < ntiles; t += nwaves) {
        const int r0 = t * 16;
        f32x4 acc[4];
        #pragma unroll
        for (int ct = 0; ct < 4; ++ct) acc[ct] = (f32x4){0.f, 0.f, 0.f, 0.f};
        #pragma unroll
        for (int ks = 0; ks < 4; ++ks) {
            short8 af = *(const short8*)(h2b + (size_t)(r0 + l15) * NHID + ks * 32 + lg * 8);
            #pragma unroll
            for (int ct = 0; ct < 4; ++ct)
                acc[ct] = __builtin_amdgcn_mfma_f32_16x16x32_bf16(af, Bf[ks][ct], acc[ct], 0, 0, 0);
        }
        #pragma unroll
        for (int ct = 0; ct < 4; ++ct)
            #pragma unroll
            for (int reg = 0; reg < 4; ++reg)
                tb[(size_t)(r0 + lg * 4 + reg) * NCLASS + ct * 16 + l15] = f2bf(acc[ct][reg]);
    }
}

// ---------------------------------------------------------------------------
// SpMM2 + b2 + log_softmax.  Wave per row, grid-stride; half-wave split:
// half h = lane>>5 processes edges lo+2i+h, lane j=lane&31 holds classes
// {2j,2j+1} via uint gather (2 x 128B per iter); halves combined by
// shfl_xor(32), softmax over 32 lanes, float2 coalesced store.
// ---------------------------------------------------------------------------
__global__ __launch_bounds__(256) void spmm2_lsm_kernel(
        const int* __restrict__ row_ptr, const int* __restrict__ cols,
        const float* __restrict__ vals, const unsigned short* __restrict__ tb,
        const float* __restrict__ b2, float* __restrict__ out, int nwaves) {
    const int lane = threadIdx.x & 63;
    const int h = lane >> 5, j = lane & 31;
    const int wave = (blockIdx.x * 256 + threadIdx.x) >> 6;
    const float bb0 = b2[2 * j], bb1 = b2[2 * j + 1];

    for (int r = wave; r < N_NODES; r += nwaves) {
        const int lo = row_ptr[r], hi = row_ptr[r + 1];
        float a0 = 0.f, a1 = 0.f;
        int e = lo;
        for (; e + 8 <= hi; e += 8) {
            #pragma unroll
            for (int q = 0; q < 4; ++q) {
                const int ee = e + 2 * q + h;
                const float vv = vals[ee];
                unsigned int p = *(const unsigned int*)(tb + (size_t)cols[ee] * NCLASS + 2 * j);
                a0 = fmaf(vv, bflo(p), a0);
                a1 = fmaf(vv, bfhi(p), a1);
            }
        }
        for (; e + 2 <= hi; e += 2) {
            const int ee = e + h;
            const float vv = vals[ee];
            unsigned int p = *(const unsigned int*)(tb + (size_t)cols[ee] * NCLASS + 2 * j);
            a0 = fmaf(vv, bflo(p), a0);
            a1 = fmaf(vv, bfhi(p), a1);
        }
        if (e < hi && h == 0) {
            const float vv = vals[e];
            unsigned int p = *(const unsigned int*)(tb + (size_t)cols[e] * NCLASS + 2 * j);
            a0 = fmaf(vv, bflo(p), a0);
            a1 = fmaf(vv, bfhi(p), a1);
        }
        // combine halves
        a0 += __shfl_xor(a0, 32, 64);
        a1 += __shfl_xor(a1, 32, 64);
        const float l0 = a0 + bb0, l1 = a1 + bb1;

        float m = fmaxf(l0, l1);
        #pragma unroll
        for (int off = 16; off > 0; off >>= 1)
            m = fmaxf(m, __shfl_xor(m, off, 64));
        float s = __expf(l0 - m) + __expf(l1 - m);
        #pragma unroll
        for (int off = 16; off > 0; off >>= 1)
            s += __shfl_xor(s, off, 64);
        const float ls = __logf(s);

        if (h == 0) {
            float2 o;
            o.x = (l0 - m) - ls;
            o.y = (l1 - m) - ls;
            *(float2*)(out + (size_t)r * NCLASS + 2 * j) = o;
        }
    }
}

// ---------------------------------------------------------------------------
// Launcher
// ---------------------------------------------------------------------------
extern "C" void kernel_launch(void* const* d_in, const int* in_sizes, int n_in,
                              void* d_out, int out_size, void* d_ws, size_t ws_size,
                              hipStream_t stream) {
    const float* x    = (const float*)d_in[0];
    const int*   rows = (const int*)  d_in[1];
    const int*   cols = (const int*)  d_in[2];
    const float* vals = (const float*)d_in[3];
    const float* W1   = (const float*)d_in[4];
    const float* b1   = (const float*)d_in[5];
    const float* W2   = (const float*)d_in[6];
    const float* b2   = (const float*)d_in[7];
    float* out = (float*)d_out;

    unsigned short* h1b = (unsigned short*)d_ws;                  // 50000*128
    unsigned short* h2b = h1b + (size_t)N_NODES * NHID;           // 50000*128
    unsigned short* tb  = h2b + (size_t)N_NODES * NHID;           // 50000*64
    unsigned short* W1T = tb  + (size_t)N_NODES * NCLASS;         // 128*512
    unsigned short* W2T = W1T + (size_t)NHID * NFEAT;             // 64*128
    int* row_ptr = (int*)(W2T + (size_t)NCLASS * NHID);           // 50001

    const int M = N_NODES;

    prep_kernel<<<2048, 256, 0, stream>>>(W1, W2, rows, W1T, W2T, row_ptr);
    gemm1_kernel<<<(M + 63) / 64, 256, 0, stream>>>(x, W1T, h1b, M);
    spmm1_kernel<<<1024, 256, 0, stream>>>(row_ptr, cols, vals, h1b, b1, h2b, 1024 * 4);
    gemm2_kernel<<<782, 256, 0, stream>>>(h2b, W2T, tb, 782 * 4);
    spmm2_lsm_kernel<<<1024, 256, 0, stream>>>(row_ptr, cols, vals, tb, b2, out, 1024 * 4);
}

// Round 5
// 256.925 us; speedup vs baseline: 1.1511x; 1.1511x over previous
//
#include <hip/hip_runtime.h>
#include <hip/hip_bf16.h>
#include <math.h>

// GCN forward, bf16 compute / fp32 accumulate:
//   prep: W1T=bf16(W1^T), W2T=bf16(W2^T), row_ptr from sorted COO rows
//   h1  = bf16( x @ W1 )             [50000,128]  MFMA 16x16x32 bf16
//   h2  = bf16( relu(A @ h1 + b1) )  [50000,128]  wave-per-row gather SpMM
//   t   = bf16( h2 @ W2 )            [50000,64]   MFMA, W2 frags in registers
//   out = log_softmax(A @ t + b2)    [50000,64]   fp32, wave-per-row
//
// SpMM gathers are widened to 16B/lane (dwordx4): spmm1 covers 4 edges per
// gather instruction (16 lanes x 16B = one 256B h1 row), spmm2 covers 8
// (8 lanes x 16B = one 128B t row). One wave per row, 50000 waves.

#define N_NODES 50000
#define N_EDGES 800000
#define NFEAT   512
#define NHID    128
#define NCLASS  64

typedef short  short8  __attribute__((ext_vector_type(8)));
typedef unsigned short ushort8 __attribute__((ext_vector_type(8)));
typedef float  f32x4   __attribute__((ext_vector_type(4)));

static __device__ __forceinline__ unsigned short f2bf(float f) {
    unsigned int b = __builtin_bit_cast(unsigned int, f);
    return (unsigned short)((b + 0x7FFFu + ((b >> 16) & 1u)) >> 16);  // RNE
}
static __device__ __forceinline__ float bf2f(unsigned short u) {
    return __builtin_bit_cast(float, ((unsigned int)u) << 16);
}

// ---------------------------------------------------------------------------
// prep: row_ptr build + W1T[n][k]=bf16(W1[k][n]) + W2T[n][k]=bf16(W2[k][n])
// ---------------------------------------------------------------------------
__global__ __launch_bounds__(256) void prep_kernel(
        const float* __restrict__ W1, const float* __restrict__ W2,
        const int* __restrict__ rows,
        unsigned short* __restrict__ W1T, unsigned short* __restrict__ W2T,
        int* __restrict__ row_ptr) {
    const int tid = blockIdx.x * 256 + threadIdx.x;
    const int T   = gridDim.x * 256;
    for (int e = tid; e < N_EDGES; e += T) {
        const int re = rows[e];
        if (e == 0) {
            for (int r = 0; r <= re; ++r) row_ptr[r] = 0;
        } else {
            const int rp = rows[e - 1];
            for (int r = rp + 1; r <= re; ++r) row_ptr[r] = e;
        }
        if (e == N_EDGES - 1) {
            for (int r = re + 1; r <= N_NODES; ++r) row_ptr[r] = N_EDGES;
        }
    }
    for (int i = tid; i < NHID * NFEAT; i += T) {
        const int n = i >> 9, k = i & 511;
        W1T[i] = f2bf(W1[(size_t)k * NHID + n]);
    }
    for (int i = tid; i < NCLASS * NHID; i += T) {
        const int n = i >> 7, k = i & 127;
        W2T[i] = f2bf(W2[(size_t)k * NCLASS + n]);
    }
}

// ---------------------------------------------------------------------------
// GEMM1 (MFMA): h1b[M,128] = bf16( x[M,512] @ W1[512,128] )
// BM=64, BN=128, BK=64; 4 waves (2x2), per wave 32x64 out.
// LDS elem (row,k) at byte row*128 + (((k>>3) ^ (row&7))<<4) + (k&7)*2.
// Validated on HW (R3/R4).
// ---------------------------------------------------------------------------
__global__ __launch_bounds__(256) void gemm1_kernel(
        const float* __restrict__ x, const unsigned short* __restrict__ W1T,
        unsigned short* __restrict__ h1b, int M) {
    __shared__ unsigned short sA[64 * 64];    // 8 KB
    __shared__ unsigned short sB[128 * 64];   // 16 KB

    const int tid  = threadIdx.x;
    const int lane = tid & 63;
    const int wid  = tid >> 6;
    const int wr   = wid >> 1, wc = wid & 1;
    const int row0 = blockIdx.x * 64;

    f32x4 acc[2][4];
    #pragma unroll
    for (int i = 0; i < 2; ++i)
        #pragma unroll
        for (int j = 0; j < 4; ++j)
            acc[i][j] = (f32x4){0.f, 0.f, 0.f, 0.f};

    const int arow = tid >> 2;           // 0..63
    const int akc  = (tid & 3) * 16;     // 16-float k-chunk
    const int bcol = tid >> 1;           // 0..127
    const int bkh  = (tid & 1) * 32;     // 32-ushort k-half

    for (int kt = 0; kt < NFEAT; kt += 64) {
        {
            float v[16];
            const float* src = x + (size_t)(row0 + arow) * NFEAT + kt + akc;
            if (row0 + arow < M) {
                #pragma unroll
                for (int i = 0; i < 4; ++i)
                    *(float4*)&v[i * 4] = *(const float4*)(src + i * 4);
            } else {
                #pragma unroll
                for (int i = 0; i < 16; ++i) v[i] = 0.f;
            }
            #pragma unroll
            for (int i2 = 0; i2 < 2; ++i2) {
                ushort8 w;
                #pragma unroll
                for (int q = 0; q < 8; ++q) w[q] = f2bf(v[i2 * 8 + q]);
                const int gran = ((akc >> 3) + i2) ^ (arow & 7);
                *(ushort8*)((char*)sA + arow * 128 + gran * 16) = w;
            }
        }
        {
            const unsigned short* srcb = W1T + (size_t)bcol * NFEAT + kt + bkh;
            #pragma unroll
            for (int i = 0; i < 4; ++i) {
                ushort8 w = *(const ushort8*)(srcb + i * 8);
                const int gran = ((bkh >> 3) + i) ^ (bcol & 7);
                *(ushort8*)((char*)sB + bcol * 128 + gran * 16) = w;
            }
        }
        __syncthreads();

        #pragma unroll
        for (int ks = 0; ks < 2; ++ks) {
            short8 af[2], bfr[4];
            #pragma unroll
            for (int i = 0; i < 2; ++i) {
                const int ar = wr * 32 + i * 16 + (lane & 15);
                const int gran = (ks * 4 + (lane >> 4)) ^ (ar & 7);
                af[i] = *(const short8*)((const char*)sA + ar * 128 + gran * 16);
            }
            #pragma unroll
            for (int j = 0; j < 4; ++j) {
                const int br = wc * 64 + j * 16 + (lane & 15);
                const int gran = (ks * 4 + (lane >> 4)) ^ (br & 7);
                bfr[j] = *(const short8*)((const char*)sB + br * 128 + gran * 16);
            }
            #pragma unroll
            for (int i = 0; i < 2; ++i)
                #pragma unroll
                for (int j = 0; j < 4; ++j)
                    acc[i][j] = __builtin_amdgcn_mfma_f32_16x16x32_bf16(
                        af[i], bfr[j], acc[i][j], 0, 0, 0);
        }
        __syncthreads();
    }

    const int cr = (lane >> 4) * 4;
    const int cc = lane & 15;
    #pragma unroll
    for (int i = 0; i < 2; ++i)
        #pragma unroll
        for (int j = 0; j < 4; ++j)
            #pragma unroll
            for (int reg = 0; reg < 4; ++reg) {
                const int row = row0 + wr * 32 + i * 16 + cr + reg;
                const int col = wc * 64 + j * 16 + cc;
                if (row < M)
                    h1b[(size_t)row * NHID + col] = f2bf(acc[i][j][reg]);
            }
}

// ---------------------------------------------------------------------------
// SpMM1: h2b[r,:] = bf16(relu( sum_e vals[e]*h1b[cols[e],:] + b1 )).
// One wave per row. Lane l: edge slot g=l>>4, feat block s=l&15 (8 feats).
// One dwordx4 gather covers 4 edges; main loop keeps 8 edges in flight.
// Combine partials with shfl_xor(16,32); lanes g==0 store 256B coalesced.
// ---------------------------------------------------------------------------
__global__ __launch_bounds__(256) void spmm1_kernel(
        const int* __restrict__ row_ptr, const int* __restrict__ cols,
        const float* __restrict__ vals, const unsigned short* __restrict__ h1b,
        const float* __restrict__ b1, unsigned short* __restrict__ h2b) {
    const int lane = threadIdx.x & 63;
    const int g = lane >> 4;          // edge slot 0..3
    const int s = lane & 15;          // feat block (feats s*8..s*8+7)
    const int r = (blockIdx.x * 256 + threadIdx.x) >> 6;
    if (r >= N_NODES) return;

    const int lo = row_ptr[r], hi = row_ptr[r + 1];
    float acc[8];
    #pragma unroll
    for (int q = 0; q < 8; ++q) acc[q] = 0.f;

    int e = lo;
    for (; e + 8 <= hi; e += 8) {
        const int e0 = e + g, e1 = e + 4 + g;
        const float v0 = __builtin_nontemporal_load(vals + e0);
        const float v1 = __builtin_nontemporal_load(vals + e1);
        const int   c0 = __builtin_nontemporal_load(cols + e0);
        const int   c1 = __builtin_nontemporal_load(cols + e1);
        const ushort8 p0 = *(const ushort8*)(h1b + (size_t)c0 * NHID + s * 8);
        const ushort8 p1 = *(const ushort8*)(h1b + (size_t)c1 * NHID + s * 8);
        #pragma unroll
        for (int q = 0; q < 8; ++q) {
            acc[q] = fmaf(v0, bf2f(p0[q]), acc[q]);
            acc[q] = fmaf(v1, bf2f(p1[q]), acc[q]);
        }
    }
    for (; e < hi; e += 4) {
        const int ee = e + g;
        ushort8 p = {0, 0, 0, 0, 0, 0, 0, 0};
        float v = 0.f;
        if (ee < hi) {
            v = vals[ee];
            const int c = cols[ee];
            p = *(const ushort8*)(h1b + (size_t)c * NHID + s * 8);
        }
        #pragma unroll
        for (int q = 0; q < 8; ++q)
            acc[q] = fmaf(v, bf2f(p[q]), acc[q]);
    }

    // combine the 4 edge slots
    #pragma unroll
    for (int q = 0; q < 8; ++q) {
        acc[q] += __shfl_xor(acc[q], 16, 64);
        acc[q] += __shfl_xor(acc[q], 32, 64);
    }

    if (g == 0) {
        float bv[8];
        *(float4*)&bv[0] = *(const float4*)(b1 + s * 8);
        *(float4*)&bv[4] = *(const float4*)(b1 + s * 8 + 4);
        ushort8 o;
        #pragma unroll
        for (int q = 0; q < 8; ++q) {
            float a = acc[q] + bv[q];
            o[q] = f2bf(a > 0.f ? a : 0.f);
        }
        *(ushort8*)(h2b + (size_t)r * NHID + s * 8) = o;
    }
}

// ---------------------------------------------------------------------------
// GEMM2 (MFMA): tb[50000,64] = bf16( h2b @ W2 ).  W2T fragments in registers;
// wave per 16-row tile (50000 = 3125*16).
// ---------------------------------------------------------------------------
__global__ __launch_bounds__(256) void gemm2_kernel(
        const unsigned short* __restrict__ h2b,
        const unsigned short* __restrict__ W2T,
        unsigned short* __restrict__ tb, int nwaves) {
    const int lane = threadIdx.x & 63;
    const int wave = (blockIdx.x * 256 + threadIdx.x) >> 6;
    const int l15 = lane & 15, lg = lane >> 4;

    short8 Bf[4][4];
    #pragma unroll
    for (int ks = 0; ks < 4; ++ks)
        #pragma unroll
        for (int ct = 0; ct < 4; ++ct)
            Bf[ks][ct] = *(const short8*)(W2T + (size_t)(ct * 16 + l15) * NHID + ks * 32 + lg * 8);

    const int ntiles = N_NODES / 16;    // 3125
    for (int t = wave; t < ntiles; t += nwaves) {
        const int r0 = t * 16;
        f32x4 acc[4];
        #pragma unroll
        for (int ct = 0; ct < 4; ++ct) acc[ct] = (f32x4){0.f, 0.f, 0.f, 0.f};
        #pragma unroll
        for (int ks = 0; ks < 4; ++ks) {
            short8 af = *(const short8*)(h2b + (size_t)(r0 + l15) * NHID + ks * 32 + lg * 8);
            #pragma unroll
            for (int ct = 0; ct < 4; ++ct)
                acc[ct] = __builtin_amdgcn_mfma_f32_16x16x32_bf16(af, Bf[ks][ct], acc[ct], 0, 0, 0);
        }
        #pragma unroll
        for (int ct = 0; ct < 4; ++ct)
            #pragma unroll
            for (int reg = 0; reg < 4; ++reg)
                tb[(size_t)(r0 + lg * 4 + reg) * NCLASS + ct * 16 + l15] = f2bf(acc[ct][reg]);
    }
}

// ---------------------------------------------------------------------------
// SpMM2 + b2 + log_softmax.  One wave per row. Lane l: edge slot g=l>>3
// (8 slots), class block s=l&7 (8 classes). One dwordx4 gather covers 8
// edges; main loop keeps 16 in flight. Combine with shfl_xor(8,16,32);
// softmax reduce over s-bits (1,2,4); lanes 0..7 store 2 x float4 each.
// ---------------------------------------------------------------------------
__global__ __launch_bounds__(256) void spmm2_lsm_kernel(
        const int* __restrict__ row_ptr, const int* __restrict__ cols,
        const float* __restrict__ vals, const unsigned short* __restrict__ tb,
        const float* __restrict__ b2, float* __restrict__ out) {
    const int lane = threadIdx.x & 63;
    const int g = lane >> 3;          // edge slot 0..7
    const int s = lane & 7;           // class block (classes s*8..s*8+7)
    const int r = (blockIdx.x * 256 + threadIdx.x) >> 6;
    if (r >= N_NODES) return;

    const int lo = row_ptr[r], hi = row_ptr[r + 1];
    float acc[8];
    #pragma unroll
    for (int q = 0; q < 8; ++q) acc[q] = 0.f;

    int e = lo;
    for (; e + 16 <= hi; e += 16) {
        const int e0 = e + g, e1 = e + 8 + g;
        const float v0 = __builtin_nontemporal_load(vals + e0);
        const float v1 = __builtin_nontemporal_load(vals + e1);
        const int   c0 = __builtin_nontemporal_load(cols + e0);
        const int   c1 = __builtin_nontemporal_load(cols + e1);
        const ushort8 p0 = *(const ushort8*)(tb + (size_t)c0 * NCLASS + s * 8);
        const ushort8 p1 = *(const ushort8*)(tb + (size_t)c1 * NCLASS + s * 8);
        #pragma unroll
        for (int q = 0; q < 8; ++q) {
            acc[q] = fmaf(v0, bf2f(p0[q]), acc[q]);
            acc[q] = fmaf(v1, bf2f(p1[q]), acc[q]);
        }
    }
    for (; e < hi; e += 8) {
        const int ee = e + g;
        ushort8 p = {0, 0, 0, 0, 0, 0, 0, 0};
        float v = 0.f;
        if (ee < hi) {
            v = vals[ee];
            const int c = cols[ee];
            p = *(const ushort8*)(tb + (size_t)c * NCLASS + s * 8);
        }
        #pragma unroll
        for (int q = 0; q < 8; ++q)
            acc[q] = fmaf(v, bf2f(p[q]), acc[q]);
    }

    // combine the 8 edge slots
    #pragma unroll
    for (int q = 0; q < 8; ++q) {
        acc[q] += __shfl_xor(acc[q], 8, 64);
        acc[q] += __shfl_xor(acc[q], 16, 64);
        acc[q] += __shfl_xor(acc[q], 32, 64);
    }

    float l[8];
    {
        float bv[8];
        *(float4*)&bv[0] = *(const float4*)(b2 + s * 8);
        *(float4*)&bv[4] = *(const float4*)(b2 + s * 8 + 4);
        #pragma unroll
        for (int q = 0; q < 8; ++q) l[q] = acc[q] + bv[q];
    }

    float m = l[0];
    #pragma unroll
    for (int q = 1; q < 8; ++q) m = fmaxf(m, l[q]);
    m = fmaxf(m, __shfl_xor(m, 1, 64));
    m = fmaxf(m, __shfl_xor(m, 2, 64));
    m = fmaxf(m, __shfl_xor(m, 4, 64));

    float sum = 0.f;
    #pragma unroll
    for (int q = 0; q < 8; ++q) sum += __expf(l[q] - m);
    sum += __shfl_xor(sum, 1, 64);
    sum += __shfl_xor(sum, 2, 64);
    sum += __shfl_xor(sum, 4, 64);
    const float ls = __logf(sum);

    if (lane < 8) {
        float4 o0, o1;
        o0.x = l[0] - m - ls; o0.y = l[1] - m - ls;
        o0.z = l[2] - m - ls; o0.w = l[3] - m - ls;
        o1.x = l[4] - m - ls; o1.y = l[5] - m - ls;
        o1.z = l[6] - m - ls; o1.w = l[7] - m - ls;
        *(float4*)(out + (size_t)r * NCLASS + s * 8)     = o0;
        *(float4*)(out + (size_t)r * NCLASS + s * 8 + 4) = o1;
    }
}

// ---------------------------------------------------------------------------
// Launcher
// ---------------------------------------------------------------------------
extern "C" void kernel_launch(void* const* d_in, const int* in_sizes, int n_in,
                              void* d_out, int out_size, void* d_ws, size_t ws_size,
                              hipStream_t stream) {
    const float* x    = (const float*)d_in[0];
    const int*   rows = (const int*)  d_in[1];
    const int*   cols = (const int*)  d_in[2];
    const float* vals = (const float*)d_in[3];
    const float* W1   = (const float*)d_in[4];
    const float* b1   = (const float*)d_in[5];
    const float* W2   = (const float*)d_in[6];
    const float* b2   = (const float*)d_in[7];
    float* out = (float*)d_out;

    unsigned short* h1b = (unsigned short*)d_ws;                  // 50000*128
    unsigned short* h2b = h1b + (size_t)N_NODES * NHID;           // 50000*128
    unsigned short* tb  = h2b + (size_t)N_NODES * NHID;           // 50000*64
    unsigned short* W1T = tb  + (size_t)N_NODES * NCLASS;         // 128*512
    unsigned short* W2T = W1T + (size_t)NHID * NFEAT;             // 64*128
    int* row_ptr = (int*)(W2T + (size_t)NCLASS * NHID);           // 50001

    const int M = N_NODES;

    prep_kernel<<<2048, 256, 0, stream>>>(W1, W2, rows, W1T, W2T, row_ptr);
    gemm1_kernel<<<(M + 63) / 64, 256, 0, stream>>>(x, W1T, h1b, M);
    spmm1_kernel<<<(M * 64 + 255) / 256, 256, 0, stream>>>(row_ptr, cols, vals, h1b, b1, h2b);
    gemm2_kernel<<<782, 256, 0, stream>>>(h2b, W2T, tb, 782 * 4);
    spmm2_lsm_kernel<<<(M * 64 + 255) / 256, 256, 0, stream>>>(row_ptr, cols, vals, tb, b2, out);
}

// Round 7
// 246.922 us; speedup vs baseline: 1.1977x; 1.0405x over previous
//
#include <hip/hip_runtime.h>
#include <hip/hip_bf16.h>
#include <math.h>

// GCN forward, bf16 compute / fp32 accumulate:
//   prep: W1T=bf16(W1^T), W2T=bf16(W2^T), row_ptr from sorted COO rows
//   h1  = bf16( x @ W1 )             [50000,128]  MFMA 16x16x32 bf16, 2-phase prefetch
//   h2  = bf16( relu(A @ h1 + b1) )  [50000,128]  wave-per-row gather SpMM
//   t   = bf16( h2 @ W2 )            [50000,64]   MFMA, W2 frags in registers
//   out = log_softmax(A @ t + b2)    [50000,64]   fp32, wave-per-row
//
// SpMM latency structure: per row, ONE coalesced edge-data load (lane l <->
// edge lo+l), __shfl broadcast of cols/vals to gather slots (no memory),
// then 4 independent 16B/lane gathers in flight. 2 dependent memory phases
// per 64 edges (vs 4-5 before).

#define N_NODES 50000
#define N_EDGES 800000
#define NFEAT   512
#define NHID    128
#define NCLASS  64

typedef short  short8  __attribute__((ext_vector_type(8)));
typedef unsigned short ushort8 __attribute__((ext_vector_type(8)));
typedef float  f32x4   __attribute__((ext_vector_type(4)));

static __device__ __forceinline__ unsigned short f2bf(float f) {
    unsigned int b = __builtin_bit_cast(unsigned int, f);
    return (unsigned short)((b + 0x7FFFu + ((b >> 16) & 1u)) >> 16);  // RNE
}
static __device__ __forceinline__ float bf2f(unsigned short u) {
    return __builtin_bit_cast(float, ((unsigned int)u) << 16);
}

// ---------------------------------------------------------------------------
// prep: row_ptr build + W1T[n][k]=bf16(W1[k][n]) + W2T[n][k]=bf16(W2[k][n])
// ---------------------------------------------------------------------------
__global__ __launch_bounds__(256) void prep_kernel(
        const float* __restrict__ W1, const float* __restrict__ W2,
        const int* __restrict__ rows,
        unsigned short* __restrict__ W1T, unsigned short* __restrict__ W2T,
        int* __restrict__ row_ptr) {
    const int tid = blockIdx.x * 256 + threadIdx.x;
    const int T   = gridDim.x * 256;
    for (int e = tid; e < N_EDGES; e += T) {
        const int re = rows[e];
        if (e == 0) {
            for (int r = 0; r <= re; ++r) row_ptr[r] = 0;
        } else {
            const int rp = rows[e - 1];
            for (int r = rp + 1; r <= re; ++r) row_ptr[r] = e;
        }
        if (e == N_EDGES - 1) {
            for (int r = re + 1; r <= N_NODES; ++r) row_ptr[r] = N_EDGES;
        }
    }
    for (int i = tid; i < NHID * NFEAT; i += T) {
        const int n = i >> 9, k = i & 511;
        W1T[i] = f2bf(W1[(size_t)k * NHID + n]);
    }
    for (int i = tid; i < NCLASS * NHID; i += T) {
        const int n = i >> 7, k = i & 127;
        W2T[i] = f2bf(W2[(size_t)k * NCLASS + n]);
    }
}

// ---------------------------------------------------------------------------
// GEMM1 (MFMA): h1b[M,128] = bf16( x[M,512] @ W1[512,128] )
// BM=64, BN=128, BK=64; 4 waves (2x2), per wave 32x64 out.
// 2-phase register prefetch: next K-tile's global loads issue right after
// this tile's LDS writes, hiding HBM latency under the 16 MFMAs.
// LDS elem (row,k) at byte row*128 + (((k>>3) ^ (row&7))<<4) + (k&7)*2.
// ---------------------------------------------------------------------------
__global__ __launch_bounds__(256) void gemm1_kernel(
        const float* __restrict__ x, const unsigned short* __restrict__ W1T,
        unsigned short* __restrict__ h1b, int M) {
    __shared__ unsigned short sA[64 * 64];    // 8 KB
    __shared__ unsigned short sB[128 * 64];   // 16 KB

    const int tid  = threadIdx.x;
    const int lane = tid & 63;
    const int wid  = tid >> 6;
    const int wr   = wid >> 1, wc = wid & 1;
    const int row0 = blockIdx.x * 64;

    f32x4 acc[2][4];
    #pragma unroll
    for (int i = 0; i < 2; ++i)
        #pragma unroll
        for (int j = 0; j < 4; ++j)
            acc[i][j] = (f32x4){0.f, 0.f, 0.f, 0.f};

    const int arow = tid >> 2;           // 0..63
    const int akc  = (tid & 3) * 16;     // 16-float k-chunk
    const int bcol = tid >> 1;           // 0..127
    const int bkh  = (tid & 1) * 32;     // 32-ushort k-half
    const bool arow_ok = (row0 + arow < M);
    const float* asrc = x + (size_t)(row0 + arow) * NFEAT + akc;
    const unsigned short* bsrc = W1T + (size_t)bcol * NFEAT + bkh;

    float   va[16];
    ushort8 vb[4];

    // prologue: load tile kt=0
    if (arow_ok) {
        #pragma unroll
        for (int i = 0; i < 4; ++i)
            *(float4*)&va[i * 4] = *(const float4*)(asrc + i * 4);
    } else {
        #pragma unroll
        for (int i = 0; i < 16; ++i) va[i] = 0.f;
    }
    #pragma unroll
    for (int i = 0; i < 4; ++i) vb[i] = *(const ushort8*)(bsrc + i * 8);

    for (int kt = 0; kt < NFEAT; kt += 64) {
        __syncthreads();   // previous iteration's LDS readers done
        // write staged regs -> LDS (A converts fp32->bf16)
        #pragma unroll
        for (int i2 = 0; i2 < 2; ++i2) {
            ushort8 w;
            #pragma unroll
            for (int q = 0; q < 8; ++q) w[q] = f2bf(va[i2 * 8 + q]);
            const int gran = ((akc >> 3) + i2) ^ (arow & 7);
            *(ushort8*)((char*)sA + arow * 128 + gran * 16) = w;
        }
        #pragma unroll
        for (int i = 0; i < 4; ++i) {
            const int gran = ((bkh >> 3) + i) ^ (bcol & 7);
            *(ushort8*)((char*)sB + bcol * 128 + gran * 16) = vb[i];
        }
        __syncthreads();

        // issue next tile's loads (hidden under MFMA below)
        const int ktn = kt + 64;
        if (ktn < NFEAT) {
            if (arow_ok) {
                #pragma unroll
                for (int i = 0; i < 4; ++i)
                    *(float4*)&va[i * 4] = *(const float4*)(asrc + ktn + i * 4);
            }
            #pragma unroll
            for (int i = 0; i < 4; ++i)
                vb[i] = *(const ushort8*)(bsrc + ktn + i * 8);
        }

        #pragma unroll
        for (int ks = 0; ks < 2; ++ks) {
            short8 af[2], bfr[4];
            #pragma unroll
            for (int i = 0; i < 2; ++i) {
                const int ar = wr * 32 + i * 16 + (lane & 15);
                const int gran = (ks * 4 + (lane >> 4)) ^ (ar & 7);
                af[i] = *(const short8*)((const char*)sA + ar * 128 + gran * 16);
            }
            #pragma unroll
            for (int j = 0; j < 4; ++j) {
                const int br = wc * 64 + j * 16 + (lane & 15);
                const int gran = (ks * 4 + (lane >> 4)) ^ (br & 7);
                bfr[j] = *(const short8*)((const char*)sB + br * 128 + gran * 16);
            }
            #pragma unroll
            for (int i = 0; i < 2; ++i)
                #pragma unroll
                for (int j = 0; j < 4; ++j)
                    acc[i][j] = __builtin_amdgcn_mfma_f32_16x16x32_bf16(
                        af[i], bfr[j], acc[i][j], 0, 0, 0);
        }
    }

    const int cr = (lane >> 4) * 4;
    const int cc = lane & 15;
    #pragma unroll
    for (int i = 0; i < 2; ++i)
        #pragma unroll
        for (int j = 0; j < 4; ++j)
            #pragma unroll
            for (int reg = 0; reg < 4; ++reg) {
                const int row = row0 + wr * 32 + i * 16 + cr + reg;
                const int col = wc * 64 + j * 16 + cc;
                if (row < M)
                    h1b[(size_t)row * NHID + col] = f2bf(acc[i][j][reg]);
            }
}

// ---------------------------------------------------------------------------
// SpMM1: h2b[r,:] = bf16(relu( sum_e vals[e]*h1b[cols[e],:] + b1 )).
// One wave per row. Lane l: gather slot g=l>>4, feat block s=l&15 (8 feats).
// Per 64-edge batch: ONE coalesced cols/vals load, shfl-broadcast to slots,
// 4 independent dwordx4 gathers (16 edges) per inner step.
// ---------------------------------------------------------------------------
__global__ __launch_bounds__(256) void spmm1_kernel(
        const int* __restrict__ row_ptr, const int* __restrict__ cols,
        const float* __restrict__ vals, const unsigned short* __restrict__ h1b,
        const float* __restrict__ b1, unsigned short* __restrict__ h2b) {
    const int lane = threadIdx.x & 63;
    const int g = lane >> 4;          // gather slot 0..3
    const int s = lane & 15;          // feat block (feats s*8..s*8+7)
    const int r = (blockIdx.x * 256 + threadIdx.x) >> 6;
    if (r >= N_NODES) return;

    const int lo = row_ptr[r], hi = row_ptr[r + 1];
    const int n = hi - lo;

    float acc[8];
    #pragma unroll
    for (int q = 0; q < 8; ++q) acc[q] = 0.f;

    for (int base = 0; base < n; base += 64) {
        const int idxl = lo + base + lane;
        const float vl = (idxl < hi) ? vals[idxl] : 0.f;
        const int   cl = (idxl < hi) ? cols[idxl] : 0;
        const int cnt = min(64, n - base);
        for (int i0 = 0; i0 < cnt; i0 += 16) {
            float v[4]; int c[4];
            #pragma unroll
            for (int u = 0; u < 4; ++u) {
                const int idx = i0 + 4 * u + g;
                v[u] = __shfl(vl, idx, 64);
                c[u] = __shfl(cl, idx, 64);
                if (idx >= cnt) { v[u] = 0.f; c[u] = 0; }
            }
            ushort8 p[4];
            #pragma unroll
            for (int u = 0; u < 4; ++u)
                p[u] = *(const ushort8*)(h1b + (size_t)c[u] * NHID + s * 8);
            #pragma unroll
            for (int u = 0; u < 4; ++u)
                #pragma unroll
                for (int q = 0; q < 8; ++q)
                    acc[q] = fmaf(v[u], bf2f(p[u][q]), acc[q]);
        }
    }

    #pragma unroll
    for (int q = 0; q < 8; ++q) {
        acc[q] += __shfl_xor(acc[q], 16, 64);
        acc[q] += __shfl_xor(acc[q], 32, 64);
    }

    if (g == 0) {
        float bv[8];
        *(float4*)&bv[0] = *(const float4*)(b1 + s * 8);
        *(float4*)&bv[4] = *(const float4*)(b1 + s * 8 + 4);
        ushort8 o;
        #pragma unroll
        for (int q = 0; q < 8; ++q) {
            float a = acc[q] + bv[q];
            o[q] = f2bf(a > 0.f ? a : 0.f);
        }
        *(ushort8*)(h2b + (size_t)r * NHID + s * 8) = o;
    }
}

// ---------------------------------------------------------------------------
// GEMM2 (MFMA): tb[50000,64] = bf16( h2b @ W2 ).  W2T fragments in registers;
// wave per 16-row tile (50000 = 3125*16).
// ---------------------------------------------------------------------------
__global__ __launch_bounds__(256) void gemm2_kernel(
        const unsigned short* __restrict__ h2b,
        const unsigned short* __restrict__ W2T,
        unsigned short* __restrict__ tb, int nwaves) {
    const int lane = threadIdx.x & 63;
    const int wave = (blockIdx.x * 256 + threadIdx.x) >> 6;
    const int l15 = lane & 15, lg = lane >> 4;

    short8 Bf[4][4];
    #pragma unroll
    for (int ks = 0; ks < 4; ++ks)
        #pragma unroll
        for (int ct = 0; ct < 4; ++ct)
            Bf[ks][ct] = *(const short8*)(W2T + (size_t)(ct * 16 + l15) * NHID + ks * 32 + lg * 8);

    const int ntiles = N_NODES / 16;    // 3125
    for (int t = wave; t < ntiles; t += nwaves) {
        const int r0 = t * 16;
        f32x4 acc[4];
        #pragma unroll
        for (int ct = 0; ct < 4; ++ct) acc[ct] = (f32x4){0.f, 0.f, 0.f, 0.f};
        #pragma unroll
        for (int ks = 0; ks < 4; ++ks) {
            short8 af = *(const short8*)(h2b + (size_t)(r0 + l15) * NHID + ks * 32 + lg * 8);
            #pragma unroll
            for (int ct = 0; ct < 4; ++ct)
                acc[ct] = __builtin_amdgcn_mfma_f32_16x16x32_bf16(af, Bf[ks][ct], acc[ct], 0, 0, 0);
        }
        #pragma unroll
        for (int ct = 0; ct < 4; ++ct)
            #pragma unroll
            for (int reg = 0; reg < 4; ++reg)
                tb[(size_t)(r0 + lg * 4 + reg) * NCLASS + ct * 16 + l15] = f2bf(acc[ct][reg]);
    }
}

// ---------------------------------------------------------------------------
// SpMM2 + b2 + log_softmax.  One wave per row. Lane l: slot g=l>>3 (8),
// class block s=l&7 (8 classes). Coalesced edge load + shfl broadcast,
// 4 independent gathers (32 edges) per inner step. Softmax over s-bits.
// ---------------------------------------------------------------------------
__global__ __launch_bounds__(256) void spmm2_lsm_kernel(
        const int* __restrict__ row_ptr, const int* __restrict__ cols,
        const float* __restrict__ vals, const unsigned short* __restrict__ tb,
        const float* __restrict__ b2, float* __restrict__ out) {
    const int lane = threadIdx.x & 63;
    const int g = lane >> 3;          // gather slot 0..7
    const int s = lane & 7;           // class block (classes s*8..s*8+7)
    const int r = (blockIdx.x * 256 + threadIdx.x) >> 6;
    if (r >= N_NODES) return;

    const int lo = row_ptr[r], hi = row_ptr[r + 1];
    const int n = hi - lo;

    float acc[8];
    #pragma unroll
    for (int q = 0; q < 8; ++q) acc[q] = 0.f;

    for (int base = 0; base < n; base += 64) {
        const int idxl = lo + base + lane;
        const float vl = (idxl < hi) ? vals[idxl] : 0.f;
        const int   cl = (idxl < hi) ? cols[idxl] : 0;
        const int cnt = min(64, n - base);
        for (int i0 = 0; i0 < cnt; i0 += 32) {
            float v[4]; int c[4];
            #pragma unroll
            for (int u = 0; u < 4; ++u) {
                const int idx = i0 + 8 * u + g;
                v[u] = __shfl(vl, idx, 64);
                c[u] = __shfl(cl, idx, 64);
                if (idx >= cnt) { v[u] = 0.f; c[u] = 0; }
            }
            ushort8 p[4];
            #pragma unroll
            for (int u = 0; u < 4; ++u)
                p[u] = *(const ushort8*)(tb + (size_t)c[u] * NCLASS + s * 8);
            #pragma unroll
            for (int u = 0; u < 4; ++u)
                #pragma unroll
                for (int q = 0; q < 8; ++q)
                    acc[q] = fmaf(v[u], bf2f(p[u][q]), acc[q]);
        }
    }

    #pragma unroll
    for (int q = 0; q < 8; ++q) {
        acc[q] += __shfl_xor(acc[q], 8, 64);
        acc[q] += __shfl_xor(acc[q], 16, 64);
        acc[q] += __shfl_xor(acc[q], 32, 64);
    }

    float l[8];
    {
        float bv[8];
        *(float4*)&bv[0] = *(const float4*)(b2 + s * 8);
        *(float4*)&bv[4] = *(const float4*)(b2 + s * 8 + 4);
        #pragma unroll
        for (int q = 0; q < 8; ++q) l[q] = acc[q] + bv[q];
    }

    float m = l[0];
    #pragma unroll
    for (int q = 1; q < 8; ++q) m = fmaxf(m, l[q]);
    m = fmaxf(m, __shfl_xor(m, 1, 64));
    m = fmaxf(m, __shfl_xor(m, 2, 64));
    m = fmaxf(m, __shfl_xor(m, 4, 64));

    float sum = 0.f;
    #pragma unroll
    for (int q = 0; q < 8; ++q) sum += __expf(l[q] - m);
    sum += __shfl_xor(sum, 1, 64);
    sum += __shfl_xor(sum, 2, 64);
    sum += __shfl_xor(sum, 4, 64);
    const float ls = __logf(sum);

    if (lane < 8) {
        float4 o0, o1;
        o0.x = l[0] - m - ls; o0.y = l[1] - m - ls;
        o0.z = l[2] - m - ls; o0.w = l[3] - m - ls;
        o1.x = l[4] - m - ls; o1.y = l[5] - m - ls;
        o1.z = l[6] - m - ls; o1.w = l[7] - m - ls;
        *(float4*)(out + (size_t)r * NCLASS + s * 8)     = o0;
        *(float4*)(out + (size_t)r * NCLASS + s * 8 + 4) = o1;
    }
}

// ---------------------------------------------------------------------------
// Launcher
// ---------------------------------------------------------------------------
extern "C" void kernel_launch(void* const* d_in, const int* in_sizes, int n_in,
                              void* d_out, int out_size, void* d_ws, size_t ws_size,
                              hipStream_t stream) {
    const float* x    = (const float*)d_in[0];
    const int*   rows = (const int*)  d_in[1];
    const int*   cols = (const int*)  d_in[2];
    const float* vals = (const float*)d_in[3];
    const float* W1   = (const float*)d_in[4];
    const float* b1   = (const float*)d_in[5];
    const float* W2   = (const float*)d_in[6];
    const float* b2   = (const float*)d_in[7];
    float* out = (float*)d_out;

    unsigned short* h1b = (unsigned short*)d_ws;                  // 50000*128
    unsigned short* h2b = h1b + (size_t)N_NODES * NHID;           // 50000*128
    unsigned short* tb  = h2b + (size_t)N_NODES * NHID;           // 50000*64
    unsigned short* W1T = tb  + (size_t)N_NODES * NCLASS;         // 128*512
    unsigned short* W2T = W1T + (size_t)NHID * NFEAT;             // 64*128
    int* row_ptr = (int*)(W2T + (size_t)NCLASS * NHID);           // 50001

    const int M = N_NODES;

    prep_kernel<<<2048, 256, 0, stream>>>(W1, W2, rows, W1T, W2T, row_ptr);
    gemm1_kernel<<<(M + 63) / 64, 256, 0, stream>>>(x, W1T, h1b, M);
    spmm1_kernel<<<(M * 64 + 255) / 256, 256, 0, stream>>>(row_ptr, cols, vals, h1b, b1, h2b);
    gemm2_kernel<<<782, 256, 0, stream>>>(h2b, W2T, tb, 782 * 4);
    spmm2_lsm_kernel<<<(M * 64 + 255) / 256, 256, 0, stream>>>(row_ptr, cols, vals, tb, b2, out);
}